// Round 1
// baseline (3087.219 us; speedup 1.0000x reference)
//
#include <hip/hip_runtime.h>
#include <hip/hip_bf16.h>

#define N_NODES 10000
#define N_EDGES 160000
#define HID 300
#define HIDP 304   // padded hidden dim
#define NPARTB (N_EDGES - N_NODES)   // 150000 independent rows

// ---------------------------------------------------------------------------
// small prep kernels
// ---------------------------------------------------------------------------

__global__ void k_edge_embed(const float* __restrict__ edge_attr,
                             const float* __restrict__ edge_w,
                             const float* __restrict__ edge_b,
                             float* __restrict__ e_buf) {
    int idx = blockIdx.x * 256 + threadIdx.x;
    if (idx >= N_EDGES * 32) return;
    int e = idx >> 5, j = idx & 31;
    const float* a = edge_attr + e * 3;
    float v = edge_b[j];
    v = fmaf(a[0], edge_w[j], v);
    v = fmaf(a[1], edge_w[32 + j], v);
    v = fmaf(a[2], edge_w[64 + j], v);
    e_buf[idx] = v;
}

__global__ void k_count(const int* __restrict__ col, int* __restrict__ cnt) {
    int e = blockIdx.x * 256 + threadIdx.x;
    if (e < N_EDGES) atomicAdd(&cnt[col[e]], 1);
}

// single-block exclusive scan over 10000 counts -> col_start[10001], cursor copy
__global__ void k_scan(const int* __restrict__ cnt, int* __restrict__ col_start,
                       int* __restrict__ cursor) {
    __shared__ int buf[256];
    __shared__ int carry;
    int t = threadIdx.x;
    if (t == 0) carry = 0;
    __syncthreads();
    for (int base = 0; base < N_NODES; base += 256) {
        int i = base + t;
        int v = (i < N_NODES) ? cnt[i] : 0;
        buf[t] = v;
        __syncthreads();
        for (int off = 1; off < 256; off <<= 1) {
            int add = (t >= off) ? buf[t - off] : 0;
            __syncthreads();
            buf[t] += add;
            __syncthreads();
        }
        int excl = buf[t] - v;
        if (i < N_NODES) { col_start[i] = carry + excl; cursor[i] = carry + excl; }
        __syncthreads();
        if (t == 0) carry += buf[255];
        __syncthreads();
    }
    if (t == 0) col_start[N_NODES] = carry;
}

__global__ void k_fill(const int* __restrict__ col, int* __restrict__ cursor,
                       int* __restrict__ edge_sorted) {
    int e = blockIdx.x * 256 + threadIdx.x;
    if (e < N_EDGES) {
        int p = atomicAdd(&cursor[col[e]], 1);
        edge_sorted[p] = e;
    }
}

__global__ void k_dinv(const int* __restrict__ cnt, float* __restrict__ dinv,
                       float* __restrict__ selfnorm) {
    int i = blockIdx.x * 256 + threadIdx.x;
    if (i < N_NODES) {
        float d = (float)cnt[i] + 1.0f;
        dinv[i] = rsqrtf(d);
        selfnorm[i] = 1.0f / d;
    }
}

__global__ void k_norm(const int* __restrict__ row, const int* __restrict__ col,
                       const float* __restrict__ dinv, float* __restrict__ norm) {
    int e = blockIdx.x * 256 + threadIdx.x;
    if (e < N_EDGES) norm[e] = dinv[row[e]] * dinv[col[e]];
}

// ---------------------------------------------------------------------------
// Part B: rows 10000..159999 — fused 5-layer per-row MLP, h kept in LDS.
// Block = 256 threads handles 32 rows. ty = t>>5 (rows 4ty..4ty+3),
// tx = t&31 (cols 10tx..10tx+9). h_lds is [k][r], stride 36 (b128-aligned,
// bank-spread). Epilogue reduces directly into g_sum (column sums for mean).
// ---------------------------------------------------------------------------
__global__ __launch_bounds__(256, 2) void k_partB(
    const float* __restrict__ e_buf,
    const float* __restrict__ w0, const float* __restrict__ b0,
    const float* __restrict__ gw, const float* __restrict__ gb,
    float* __restrict__ g_sum) {
    __shared__ float h_lds[HIDP * 36];   // 43776 B
    __shared__ float w_lds[16 * 320];    // 20480 B  (total 64256 B < 64 KiB)
    int t = threadIdx.x;
    int ty = t >> 5;
    int tx = t & 31;
    int row0 = N_NODES + blockIdx.x * 32;

    // stage layer-0 input [k][r] from e_buf (row-major [E][32]); zero-fill tail
    for (int q = t; q < 32 * 32; q += 256) {
        int r = q >> 5, k = q & 31;
        int gr = row0 + r;
        h_lds[k * 36 + r] = (gr < N_EDGES) ? e_buf[gr * 32 + k] : 0.0f;
    }
    __syncthreads();

    float acc[4][10];
    for (int layer = 0; layer < 5; ++layer) {
        const float* wptr = (layer == 0) ? w0 : gw + (layer - 1) * HID * HID;
        const float* bptr = (layer == 0) ? b0 : gb + (layer - 1) * HID;
        int K_iter = (layer == 0) ? 32 : HIDP;
        int K_w = (layer == 0) ? 32 : HID;
#pragma unroll
        for (int i = 0; i < 4; ++i)
#pragma unroll
            for (int j = 0; j < 10; ++j) acc[i][j] = 0.0f;

        for (int k0 = 0; k0 < K_iter; k0 += 16) {
            __syncthreads();  // protect w_lds from previous readers
            // stage 16x320 weight chunk (zero-padded)
            for (int f = t; f < 16 * 80; f += 256) {
                int k = f / 80, n = (f % 80) * 4;
                float4 v = make_float4(0.f, 0.f, 0.f, 0.f);
                int kk = k0 + k;
                if (kk < K_w && n < HID) v = *(const float4*)(wptr + kk * HID + n);
                *(float4*)&w_lds[k * 320 + n] = v;
            }
            __syncthreads();
#pragma unroll 4
            for (int k = 0; k < 16; ++k) {
                float4 hv = *(const float4*)&h_lds[(k0 + k) * 36 + 4 * ty];
                float h4[4] = {hv.x, hv.y, hv.z, hv.w};
                float wv[10];
#pragma unroll
                for (int j = 0; j < 5; ++j) {
                    float2 w2 = *(const float2*)&w_lds[k * 320 + tx * 10 + 2 * j];
                    wv[2 * j] = w2.x; wv[2 * j + 1] = w2.y;
                }
#pragma unroll
                for (int i = 0; i < 4; ++i)
#pragma unroll
                    for (int j = 0; j < 10; ++j)
                        acc[i][j] = fmaf(h4[i], wv[j], acc[i][j]);
            }
        }
        // bias + relu (part-B rows: self_norm = 1, agg = 0)
        float bb[10];
#pragma unroll
        for (int j = 0; j < 10; ++j) {
            int c = tx * 10 + j;
            bb[j] = (c < HID) ? bptr[c] : 0.0f;
        }
#pragma unroll
        for (int i = 0; i < 4; ++i)
#pragma unroll
            for (int j = 0; j < 10; ++j)
                acc[i][j] = fmaxf(acc[i][j] + bb[j], 0.0f);

        if (layer < 4) {
            __syncthreads();  // all reads of old h done
#pragma unroll
            for (int j = 0; j < 10; ++j) {
                int c = tx * 10 + j;
                if (c < HIDP) {
                    float4 v = make_float4(acc[0][j], acc[1][j], acc[2][j], acc[3][j]);
                    *(float4*)&h_lds[c * 36 + 4 * ty] = v;
                }
            }
            __syncthreads();
        }
    }

    // column partial sums of final h (mask rows beyond E)
    float s[10];
#pragma unroll
    for (int j = 0; j < 10; ++j) {
        s[j] = 0.0f;
#pragma unroll
        for (int i = 0; i < 4; ++i) {
            int gr = row0 + 4 * ty + i;
            if (gr < N_EDGES) s[j] += acc[i][j];
        }
    }
    __syncthreads();
#pragma unroll
    for (int j = 0; j < 10; ++j) w_lds[ty * 320 + tx * 10 + j] = s[j];
    __syncthreads();
    if (ty == 0) {
        for (int j = 0; j < 10; ++j) {
            int c = tx * 10 + j;
            if (c < HID) {
                float tot = 0.0f;
#pragma unroll
                for (int g = 0; g < 8; ++g) tot += w_lds[g * 320 + tx * 10 + j];
                atomicAdd(&g_sum[c], tot);
            }
        }
    }
}

// ---------------------------------------------------------------------------
// Part A GEMM: hw[10000][304] = A[10000][lda] @ W[K][300] (raw, no epilogue)
// BM=128 BN=64 BK=16, 256 threads, 8x4 microtile.
// ---------------------------------------------------------------------------
__global__ __launch_bounds__(256) void k_gemmA(const float* __restrict__ A, int lda,
                                               int K_iter, int K_w,
                                               const float* __restrict__ W,
                                               float* __restrict__ HW) {
    __shared__ float a_lds[16 * 132];
    __shared__ float b_lds[16 * 68];
    int t = threadIdx.x;
    int tx = t & 15;
    int ty = t >> 4;
    int m0 = blockIdx.x * 128;
    int n0 = blockIdx.y * 64;
    float acc[8][4];
#pragma unroll
    for (int i = 0; i < 8; ++i)
#pragma unroll
        for (int j = 0; j < 4; ++j) acc[i][j] = 0.0f;

    for (int k0 = 0; k0 < K_iter; k0 += 16) {
        __syncthreads();
#pragma unroll
        for (int s = 0; s < 8; ++s) {
            int f = t + 256 * s;
            int k = f & 15, m = f >> 4;
            int gm = m0 + m, gk = k0 + k;
            a_lds[k * 132 + m] = (gm < N_NODES && gk < K_iter) ? A[gm * lda + gk] : 0.0f;
        }
        {
            int k = t >> 4, n = (t & 15) * 4;
            int gk = k0 + k, gn = n0 + n;
            float4 v = make_float4(0.f, 0.f, 0.f, 0.f);
            if (gk < K_w && gn < HID) v = *(const float4*)(W + gk * HID + gn);
            *(float4*)&b_lds[k * 68 + n] = v;
        }
        __syncthreads();
#pragma unroll
        for (int k = 0; k < 16; ++k) {
            float4 aa = *(const float4*)&a_lds[k * 132 + 8 * ty];
            float4 ab = *(const float4*)&a_lds[k * 132 + 8 * ty + 4];
            float4 bv = *(const float4*)&b_lds[k * 68 + 4 * tx];
            float a8[8] = {aa.x, aa.y, aa.z, aa.w, ab.x, ab.y, ab.z, ab.w};
            float b4[4] = {bv.x, bv.y, bv.z, bv.w};
#pragma unroll
            for (int i = 0; i < 8; ++i)
#pragma unroll
                for (int j = 0; j < 4; ++j)
                    acc[i][j] = fmaf(a8[i], b4[j], acc[i][j]);
        }
    }
#pragma unroll
    for (int i = 0; i < 8; ++i) {
        int gm = m0 + 8 * ty + i;
        if (gm < N_NODES) {
#pragma unroll
            for (int j = 0; j < 4; ++j) {
                int gn = n0 + 4 * tx + j;
                if (gn < HIDP) HW[gm * HIDP + gn] = acc[i][j];
            }
        }
    }
}

// ---------------------------------------------------------------------------
// Part A aggregation: one block per destination node c.
// out[c] = relu( sum_{e in CSR[c]} norm[e]*hw[row[e]] + selfnorm[c]*hw[c] + b )
// ---------------------------------------------------------------------------
__global__ void k_aggA(const float* __restrict__ hw, const int* __restrict__ col_start,
                       const int* __restrict__ edge_sorted, const int* __restrict__ row,
                       const float* __restrict__ norm, const float* __restrict__ selfnorm,
                       const float* __restrict__ bias, float* __restrict__ out) {
    __shared__ int s_row[64];
    __shared__ float s_norm[64];
    int c = blockIdx.x;
    int t = threadIdx.x;
    int beg = col_start[c], end = col_start[c + 1];
    float sn = selfnorm[c];
    float v0 = 0.0f, v1 = 0.0f;
    for (int base = beg; base < end; base += 64) {
        int m = min(64, end - base);
        if (t < m) {
            int e = edge_sorted[base + t];
            s_row[t] = row[e];
            s_norm[t] = norm[e];
        }
        __syncthreads();
        for (int i = 0; i < m; ++i) {
            int rr = s_row[i];
            float nn = s_norm[i];
            v0 = fmaf(nn, hw[rr * HIDP + t], v0);
            if (t < HIDP - 256) v1 = fmaf(nn, hw[rr * HIDP + 256 + t], v1);
        }
        __syncthreads();
    }
    float h0 = v0 + sn * hw[c * HIDP + t] + ((t < HID) ? bias[t] : 0.0f);
    out[c * HIDP + t] = fmaxf(h0, 0.0f);
    if (t < HIDP - 256) {
        int d = 256 + t;
        float h1 = v1 + sn * hw[c * HIDP + d] + ((d < HID) ? bias[d] : 0.0f);
        out[c * HIDP + d] = fmaxf(h1, 0.0f);
    }
}

__global__ void k_colsumA(const float* __restrict__ h, float* __restrict__ g_sum) {
    int r0 = blockIdx.x * 64;
    int t = threadIdx.x;
    float s0 = 0.0f, s1 = 0.0f;
    for (int r = 0; r < 64; ++r) {
        int gr = r0 + r;
        if (gr < N_NODES) {
            s0 += h[gr * HIDP + t];
            if (t < HIDP - 256) s1 += h[gr * HIDP + 256 + t];
        }
    }
    if (t < HID) atomicAdd(&g_sum[t], s0);
    if (t < HIDP - 256 && 256 + t < HID) atomicAdd(&g_sum[256 + t], s1);
}

__global__ void k_head(const float* __restrict__ g_sum,
                       const float* __restrict__ lin1_w, const float* __restrict__ lin1_b,
                       const float* __restrict__ lin2_w, const float* __restrict__ lin2_b,
                       float* __restrict__ out) {
    __shared__ float g2[32];
    int t = threadIdx.x;
    const float inv = 1.0f / (float)N_EDGES;
    if (t < 32) {
        float a = lin1_b[t];
        for (int d = 0; d < HID; ++d) a = fmaf(g_sum[d] * inv, lin1_w[d * 32 + t], a);
        g2[t] = fmaxf(a, 0.0f);
    }
    __syncthreads();
    if (t < 2) {
        float p = lin2_b[t];
        for (int j = 0; j < 32; ++j) p = fmaf(g2[j], lin2_w[j * 2 + t], p);
        out[t] = p;
    }
}

// ---------------------------------------------------------------------------

extern "C" void kernel_launch(void* const* d_in, const int* in_sizes, int n_in,
                              void* d_out, int out_size, void* d_ws, size_t ws_size,
                              hipStream_t stream) {
    (void)in_sizes; (void)n_in; (void)out_size; (void)ws_size;
    const int* edge_index = (const int*)d_in[1];
    const float* edge_attr = (const float*)d_in[2];
    const float* edge_w = (const float*)d_in[6];
    const float* edge_b = (const float*)d_in[7];
    const float* gcn0_w = (const float*)d_in[8];
    const float* gcn0_b = (const float*)d_in[9];
    const float* gcn_w = (const float*)d_in[10];
    const float* gcn_b = (const float*)d_in[11];
    const float* lin1_w = (const float*)d_in[12];
    const float* lin1_b = (const float*)d_in[13];
    const float* lin2_w = (const float*)d_in[14];
    const float* lin2_b = (const float*)d_in[15];

    char* ws = (char*)d_ws;
    size_t off = 0;
    auto alloc = [&](size_t bytes) {
        void* p = ws + off;
        off = (off + bytes + 255) & ~(size_t)255;
        return p;
    };
    float* e_buf = (float*)alloc((size_t)N_EDGES * 32 * 4);       // 20.48 MB
    float* hA = (float*)alloc((size_t)N_NODES * HIDP * 4);        // 12.16 MB
    float* hB = (float*)alloc((size_t)N_NODES * HIDP * 4);        // 12.16 MB
    float* hw = (float*)alloc((size_t)N_NODES * HIDP * 4);        // 12.16 MB
    float* norm = (float*)alloc((size_t)N_EDGES * 4);
    int* edge_sorted = (int*)alloc((size_t)N_EDGES * 4);
    int* cnt = (int*)alloc((size_t)N_NODES * 4);
    int* col_start = (int*)alloc((size_t)(N_NODES + 1) * 4);
    int* cursor = (int*)alloc((size_t)N_NODES * 4);
    float* dinv = (float*)alloc((size_t)N_NODES * 4);
    float* selfnorm = (float*)alloc((size_t)N_NODES * 4);
    float* g_sum = (float*)alloc((size_t)HIDP * 4);

    const int* row = edge_index;
    const int* col = edge_index + N_EDGES;

    hipMemsetAsync(cnt, 0, N_NODES * 4, stream);
    hipMemsetAsync(g_sum, 0, HIDP * 4, stream);

    k_edge_embed<<<(N_EDGES * 32 + 255) / 256, 256, 0, stream>>>(edge_attr, edge_w, edge_b, e_buf);
    k_count<<<(N_EDGES + 255) / 256, 256, 0, stream>>>(col, cnt);
    k_scan<<<1, 256, 0, stream>>>(cnt, col_start, cursor);
    k_fill<<<(N_EDGES + 255) / 256, 256, 0, stream>>>(col, cursor, edge_sorted);
    k_dinv<<<(N_NODES + 255) / 256, 256, 0, stream>>>(cnt, dinv, selfnorm);
    k_norm<<<(N_EDGES + 255) / 256, 256, 0, stream>>>(row, col, dinv, norm);

    // Part B: dominant fused kernel (150000 rows, 5 layers, ~110 GFLOP)
    k_partB<<<(NPARTB + 31) / 32, 256, 0, stream>>>(e_buf, gcn0_w, gcn0_b, gcn_w, gcn_b, g_sum);

    // Part A: coupled top-10000 rows, layer by layer
    dim3 gA((N_NODES + 127) / 128, (HIDP + 63) / 64);
    k_gemmA<<<gA, 256, 0, stream>>>(e_buf, 32, 32, 32, gcn0_w, hw);
    k_aggA<<<N_NODES, 256, 0, stream>>>(hw, col_start, edge_sorted, row, norm, selfnorm, gcn0_b, hA);
    float* curr = hA;
    float* next = hB;
    for (int l = 1; l < 5; ++l) {
        k_gemmA<<<gA, 256, 0, stream>>>(curr, HIDP, HIDP, HID, gcn_w + (l - 1) * HID * HID, hw);
        k_aggA<<<N_NODES, 256, 0, stream>>>(hw, col_start, edge_sorted, row, norm, selfnorm,
                                            gcn_b + (l - 1) * HID, next);
        float* tmp = curr; curr = next; next = tmp;
    }
    k_colsumA<<<(N_NODES + 63) / 64, 256, 0, stream>>>(curr, g_sum);
    k_head<<<1, 64, 0, stream>>>(g_sum, lin1_w, lin1_b, lin2_w, lin2_b, (float*)d_out);
}

// Round 2
// 1499.654 us; speedup vs baseline: 2.0586x; 2.0586x over previous
//
#include <hip/hip_runtime.h>
#include <hip/hip_bf16.h>

#define N_NODES 10000
#define N_EDGES 160000
#define HID 300
#define HIDP 304   // padded hidden dim (Part A buffers)
#define NPARTB (N_EDGES - N_NODES)   // 150000 independent rows
#define HSTRIDE 316                  // Part-B LDS row stride (fp32), 2-way-bank-safe

typedef __attribute__((ext_vector_type(8))) short short8;
typedef __attribute__((ext_vector_type(4))) float f32x4;

#define MFMA_B16(a, b, c) __builtin_amdgcn_mfma_f32_16x16x32_bf16(a, b, c, 0, 0, 0)

// ---------------------------------------------------------------------------
// small prep kernels
// ---------------------------------------------------------------------------

__global__ void k_edge_embed(const float* __restrict__ edge_attr,
                             const float* __restrict__ edge_w,
                             const float* __restrict__ edge_b,
                             float* __restrict__ e_buf) {
    int idx = blockIdx.x * 256 + threadIdx.x;
    if (idx >= N_EDGES * 32) return;
    int e = idx >> 5, j = idx & 31;
    const float* a = edge_attr + e * 3;
    float v = edge_b[j];
    v = fmaf(a[0], edge_w[j], v);
    v = fmaf(a[1], edge_w[32 + j], v);
    v = fmaf(a[2], edge_w[64 + j], v);
    e_buf[idx] = v;
}

__global__ void k_count(const int* __restrict__ col, int* __restrict__ cnt) {
    int e = blockIdx.x * 256 + threadIdx.x;
    if (e < N_EDGES) atomicAdd(&cnt[col[e]], 1);
}

__global__ void k_scan(const int* __restrict__ cnt, int* __restrict__ col_start,
                       int* __restrict__ cursor) {
    __shared__ int buf[256];
    __shared__ int carry;
    int t = threadIdx.x;
    if (t == 0) carry = 0;
    __syncthreads();
    for (int base = 0; base < N_NODES; base += 256) {
        int i = base + t;
        int v = (i < N_NODES) ? cnt[i] : 0;
        buf[t] = v;
        __syncthreads();
        for (int off = 1; off < 256; off <<= 1) {
            int add = (t >= off) ? buf[t - off] : 0;
            __syncthreads();
            buf[t] += add;
            __syncthreads();
        }
        int excl = buf[t] - v;
        if (i < N_NODES) { col_start[i] = carry + excl; cursor[i] = carry + excl; }
        __syncthreads();
        if (t == 0) carry += buf[255];
        __syncthreads();
    }
    if (t == 0) col_start[N_NODES] = carry;
}

__global__ void k_fill(const int* __restrict__ col, int* __restrict__ cursor,
                       int* __restrict__ edge_sorted) {
    int e = blockIdx.x * 256 + threadIdx.x;
    if (e < N_EDGES) {
        int p = atomicAdd(&cursor[col[e]], 1);
        edge_sorted[p] = e;
    }
}

__global__ void k_dinv(const int* __restrict__ cnt, float* __restrict__ dinv,
                       float* __restrict__ selfnorm) {
    int i = blockIdx.x * 256 + threadIdx.x;
    if (i < N_NODES) {
        float d = (float)cnt[i] + 1.0f;
        dinv[i] = rsqrtf(d);
        selfnorm[i] = 1.0f / d;
    }
}

__global__ void k_norm(const int* __restrict__ row, const int* __restrict__ col,
                       const float* __restrict__ dinv, float* __restrict__ norm) {
    int e = blockIdx.x * 256 + threadIdx.x;
    if (e < N_EDGES) norm[e] = dinv[row[e]] * dinv[col[e]];
}

// ---------------------------------------------------------------------------
// Weight pre-split: fp32 W[k][n] -> bf16 hi/lo in MFMA-B-fragment swizzled
// layout so one wave load = 1 KB contiguous.
// Layer 0 (K=32):  wt0 [nt:19][h:2][q:4][n16:16][j:8] shorts  (38912 B)
// Layers 1-4:      wtl [l:4][chunk:10][nt:19][h:2][q:4][n16:16][j:8]
//                  (389120 B per layer); k>=300 or n>=300 zero-padded.
// ---------------------------------------------------------------------------
__global__ void k_wt(const float* __restrict__ g0w, const float* __restrict__ gw,
                     short* __restrict__ wt0, short* __restrict__ wtl) {
    int idx = blockIdx.x * 256 + threadIdx.x;
    if (idx < 1216) {  // layer 0: 19*4*16 groups
        int n16 = idx & 15, q = (idx >> 4) & 3, nt = idx >> 6;
        int n = nt * 16 + n16;
        short* hd = wt0 + (size_t)(nt * 8 + q) * 128 + n16 * 8;
        short* ld = wt0 + (size_t)(nt * 8 + 4 + q) * 128 + n16 * 8;
#pragma unroll
        for (int j = 0; j < 8; ++j) {
            int k = q * 8 + j;
            float f = (n < HID) ? g0w[k * HID + n] : 0.0f;
            unsigned u = __float_as_uint(f);
            unsigned h = (u + 0x7fffu + ((u >> 16) & 1u)) >> 16;
            float hf = __uint_as_float(h << 16);
            unsigned v = __float_as_uint(f - hf);
            unsigned lo = (v + 0x7fffu + ((v >> 16) & 1u)) >> 16;
            hd[j] = (short)h;
            ld[j] = (short)lo;
        }
    } else if (idx < 1216 + 48640) {
        int i = idx - 1216;
        int n16 = i & 15; i >>= 4;
        int q = i & 3; i >>= 2;
        int nt = i % 19; i /= 19;
        int chunk = i % 10;
        int l = i / 10;
        int n = nt * 16 + n16;
        int cnt_idx = chunk * 19 + nt;
        short* base = wtl + (size_t)l * 194560;
        short* hd = base + (size_t)(cnt_idx * 8 + q) * 128 + n16 * 8;
        short* ld = base + (size_t)(cnt_idx * 8 + 4 + q) * 128 + n16 * 8;
#pragma unroll
        for (int j = 0; j < 8; ++j) {
            int k = chunk * 32 + q * 8 + j;
            float f = (k < HID && n < HID) ? gw[((size_t)l * HID + k) * HID + n] : 0.0f;
            unsigned u = __float_as_uint(f);
            unsigned h = (u + 0x7fffu + ((u >> 16) & 1u)) >> 16;
            float hf = __uint_as_float(h << 16);
            unsigned v = __float_as_uint(f - hf);
            unsigned lo = (v + 0x7fffu + ((v >> 16) & 1u)) >> 16;
            hd[j] = (short)h;
            ld[j] = (short)lo;
        }
    }
}

// ---------------------------------------------------------------------------
// Part B (MFMA): 1 wave (64 thr) per block, 32 rows/wave, rows fully
// independent -> zero barriers in main loop. H fp32 in LDS [32][HSTRIDE];
// split-bf16 3-term MFMA (Ah*Bh + Ah*Bl + Al*Bh), input precision ~2^-18.
// ---------------------------------------------------------------------------

__device__ __forceinline__ void split8(const float* a, short8& hi, short8& lo) {
#pragma unroll
    for (int j = 0; j < 8; ++j) {
        float x = a[j];
        unsigned u = __float_as_uint(x);
        unsigned h = (u + 0x7fffu + ((u >> 16) & 1u)) >> 16;
        float hf = __uint_as_float(h << 16);
        float d = x - hf;
        unsigned v = __float_as_uint(d);
        unsigned l = (v + 0x7fffu + ((v >> 16) & 1u)) >> 16;
        hi[j] = (short)h;
        lo[j] = (short)l;
    }
}

__global__ __launch_bounds__(64, 1) void k_partB_mfma(
    const float* __restrict__ e_buf,
    const short* __restrict__ wt0,
    const short* __restrict__ wtl,
    const float* __restrict__ b0,
    const float* __restrict__ gb,
    float* __restrict__ g_part) {
    __shared__ float H[32 * HSTRIDE];   // 40448 B -> 4 blocks/CU
    int lane = threadIdx.x;
    int l16 = lane & 15;
    int quad = lane >> 4;
    int base = N_NODES + blockIdx.x * 32;

    f32x4 acc[2][19];
    short8 ahi[2], alo[2];

    // ---------------- layer 0 (K=32) ----------------
#pragma unroll
    for (int mt = 0; mt < 2; ++mt)
#pragma unroll
        for (int nt = 0; nt < 19; ++nt)
#pragma unroll
            for (int r = 0; r < 4; ++r) acc[mt][nt][r] = 0.0f;

#pragma unroll
    for (int mt = 0; mt < 2; ++mt) {
        int gr = base + mt * 16 + l16;
        float a8[8];
        if (gr < N_EDGES) {
            float4 t0 = *(const float4*)(e_buf + (size_t)gr * 32 + quad * 8);
            float4 t1 = *(const float4*)(e_buf + (size_t)gr * 32 + quad * 8 + 4);
            a8[0] = t0.x; a8[1] = t0.y; a8[2] = t0.z; a8[3] = t0.w;
            a8[4] = t1.x; a8[5] = t1.y; a8[6] = t1.z; a8[7] = t1.w;
        } else {
#pragma unroll
            for (int j = 0; j < 8; ++j) a8[j] = 0.0f;
        }
        split8(a8, ahi[mt], alo[mt]);
    }
#pragma unroll
    for (int nt = 0; nt < 19; ++nt) {
        const short* p = wt0 + (size_t)(nt * 8 + quad) * 128 + l16 * 8;
        short8 bh = *(const short8*)p;
        short8 bl = *(const short8*)(p + 512);
        acc[0][nt] = MFMA_B16(ahi[0], bh, acc[0][nt]);
        acc[0][nt] = MFMA_B16(ahi[0], bl, acc[0][nt]);
        acc[0][nt] = MFMA_B16(alo[0], bh, acc[0][nt]);
        acc[1][nt] = MFMA_B16(ahi[1], bh, acc[1][nt]);
        acc[1][nt] = MFMA_B16(ahi[1], bl, acc[1][nt]);
        acc[1][nt] = MFMA_B16(alo[1], bh, acc[1][nt]);
    }
    // store layer-0 output: relu(acc + b0)
#pragma unroll
    for (int nt = 0; nt < 19; ++nt) {
        int c = nt * 16 + l16;
        float b = (c < HID) ? b0[c] : 0.0f;
#pragma unroll
        for (int mt = 0; mt < 2; ++mt)
#pragma unroll
            for (int r = 0; r < 4; ++r)
                H[(mt * 16 + quad * 4 + r) * HSTRIDE + c] =
                    fmaxf(acc[mt][nt][r] + b, 0.0f);
    }

    // ---------------- layers 1..4 (K=304, 10 chunks, chunk 9 half-masked) ---
    for (int l = 0; l < 4; ++l) {
        const short* wl = wtl + (size_t)l * 194560;
        const float* bias = gb + l * HID;
#pragma unroll
        for (int mt = 0; mt < 2; ++mt)
#pragma unroll
            for (int nt = 0; nt < 19; ++nt)
#pragma unroll
                for (int r = 0; r < 4; ++r) acc[mt][nt][r] = 0.0f;

        for (int chunk = 0; chunk < 10; ++chunk) {
            bool dead = (chunk == 9) && (quad >= 2);
            int kb = dead ? 288 : (chunk * 32 + quad * 8);
#pragma unroll
            for (int mt = 0; mt < 2; ++mt) {
                const float* hp = &H[(mt * 16 + l16) * HSTRIDE + kb];
                float4 t0 = *(const float4*)hp;
                float4 t1 = *(const float4*)(hp + 4);
                float a8[8] = {t0.x, t0.y, t0.z, t0.w, t1.x, t1.y, t1.z, t1.w};
                split8(a8, ahi[mt], alo[mt]);
                if (dead) {
#pragma unroll
                    for (int j = 0; j < 8; ++j) { ahi[mt][j] = 0; alo[mt][j] = 0; }
                }
            }
            const short* cbase = wl + (size_t)(chunk * 19) * 1024 + quad * 128 + l16 * 8;
#pragma unroll
            for (int nt = 0; nt < 19; ++nt) {
                const short* p = cbase + (size_t)nt * 1024;
                short8 bh = *(const short8*)p;
                short8 bl = *(const short8*)(p + 512);
                acc[0][nt] = MFMA_B16(ahi[0], bh, acc[0][nt]);
                acc[0][nt] = MFMA_B16(ahi[0], bl, acc[0][nt]);
                acc[0][nt] = MFMA_B16(alo[0], bh, acc[0][nt]);
                acc[1][nt] = MFMA_B16(ahi[1], bh, acc[1][nt]);
                acc[1][nt] = MFMA_B16(ahi[1], bl, acc[1][nt]);
                acc[1][nt] = MFMA_B16(alo[1], bh, acc[1][nt]);
            }
        }

        if (l < 3) {
#pragma unroll
            for (int nt = 0; nt < 19; ++nt) {
                int c = nt * 16 + l16;
                float b = (c < HID) ? bias[c] : 0.0f;
#pragma unroll
                for (int mt = 0; mt < 2; ++mt)
#pragma unroll
                    for (int r = 0; r < 4; ++r)
                        H[(mt * 16 + quad * 4 + r) * HSTRIDE + c] =
                            fmaxf(acc[mt][nt][r] + b, 0.0f);
            }
        } else {
            // final layer: relu + masked column sums, no H store
            int valid = N_EDGES - base;
            if (valid > 32) valid = 32;
#pragma unroll
            for (int nt = 0; nt < 19; ++nt) {
                int c = nt * 16 + l16;
                float b = (c < HID) ? bias[c] : 0.0f;
                float s = 0.0f;
#pragma unroll
                for (int mt = 0; mt < 2; ++mt)
#pragma unroll
                    for (int r = 0; r < 4; ++r) {
                        int rr = mt * 16 + quad * 4 + r;
                        float v = fmaxf(acc[mt][nt][r] + b, 0.0f);
                        if (rr < valid) s += v;
                    }
                s += __shfl_xor(s, 16, 64);
                s += __shfl_xor(s, 32, 64);
                if (quad == 0 && c < HID)
                    atomicAdd(&g_part[(blockIdx.x & 63) * HIDP + c], s);
            }
        }
    }
}

__global__ void k_gsum(const float* __restrict__ g_part, float* __restrict__ g_sum) {
    int c = blockIdx.x * 256 + threadIdx.x;
    if (c < HID) {
        float s = 0.0f;
        for (int g = 0; g < 64; ++g) s += g_part[g * HIDP + c];
        atomicAdd(&g_sum[c], s);
    }
}

// ---------------------------------------------------------------------------
// Part A GEMM: hw[10000][304] = A[10000][lda] @ W[K][300]
// ---------------------------------------------------------------------------
__global__ __launch_bounds__(256) void k_gemmA(const float* __restrict__ A, int lda,
                                               int K_iter, int K_w,
                                               const float* __restrict__ W,
                                               float* __restrict__ HW) {
    __shared__ float a_lds[16 * 132];
    __shared__ float b_lds[16 * 68];
    int t = threadIdx.x;
    int tx = t & 15;
    int ty = t >> 4;
    int m0 = blockIdx.x * 128;
    int n0 = blockIdx.y * 64;
    float acc[8][4];
#pragma unroll
    for (int i = 0; i < 8; ++i)
#pragma unroll
        for (int j = 0; j < 4; ++j) acc[i][j] = 0.0f;

    for (int k0 = 0; k0 < K_iter; k0 += 16) {
        __syncthreads();
#pragma unroll
        for (int s = 0; s < 8; ++s) {
            int f = t + 256 * s;
            int k = f & 15, m = f >> 4;
            int gm = m0 + m, gk = k0 + k;
            a_lds[k * 132 + m] = (gm < N_NODES && gk < K_iter) ? A[gm * lda + gk] : 0.0f;
        }
        {
            int k = t >> 4, n = (t & 15) * 4;
            int gk = k0 + k, gn = n0 + n;
            float4 v = make_float4(0.f, 0.f, 0.f, 0.f);
            if (gk < K_w && gn < HID) v = *(const float4*)(W + gk * HID + gn);
            *(float4*)&b_lds[k * 68 + n] = v;
        }
        __syncthreads();
#pragma unroll
        for (int k = 0; k < 16; ++k) {
            float4 aa = *(const float4*)&a_lds[k * 132 + 8 * ty];
            float4 ab = *(const float4*)&a_lds[k * 132 + 8 * ty + 4];
            float4 bv = *(const float4*)&b_lds[k * 68 + 4 * tx];
            float a8[8] = {aa.x, aa.y, aa.z, aa.w, ab.x, ab.y, ab.z, ab.w};
            float b4[4] = {bv.x, bv.y, bv.z, bv.w};
#pragma unroll
            for (int i = 0; i < 8; ++i)
#pragma unroll
                for (int j = 0; j < 4; ++j)
                    acc[i][j] = fmaf(a8[i], b4[j], acc[i][j]);
        }
    }
#pragma unroll
    for (int i = 0; i < 8; ++i) {
        int gm = m0 + 8 * ty + i;
        if (gm < N_NODES) {
#pragma unroll
            for (int j = 0; j < 4; ++j) {
                int gn = n0 + 4 * tx + j;
                if (gn < HIDP) HW[gm * HIDP + gn] = acc[i][j];
            }
        }
    }
}

// ---------------------------------------------------------------------------
// Part A aggregation
// ---------------------------------------------------------------------------
__global__ void k_aggA(const float* __restrict__ hw, const int* __restrict__ col_start,
                       const int* __restrict__ edge_sorted, const int* __restrict__ row,
                       const float* __restrict__ norm, const float* __restrict__ selfnorm,
                       const float* __restrict__ bias, float* __restrict__ out) {
    __shared__ int s_row[64];
    __shared__ float s_norm[64];
    int c = blockIdx.x;
    int t = threadIdx.x;
    int beg = col_start[c], end = col_start[c + 1];
    float sn = selfnorm[c];
    float v0 = 0.0f, v1 = 0.0f;
    for (int base = beg; base < end; base += 64) {
        int m = min(64, end - base);
        if (t < m) {
            int e = edge_sorted[base + t];
            s_row[t] = row[e];
            s_norm[t] = norm[e];
        }
        __syncthreads();
        for (int i = 0; i < m; ++i) {
            int rr = s_row[i];
            float nn = s_norm[i];
            v0 = fmaf(nn, hw[rr * HIDP + t], v0);
            if (t < HIDP - 256) v1 = fmaf(nn, hw[rr * HIDP + 256 + t], v1);
        }
        __syncthreads();
    }
    float h0 = v0 + sn * hw[c * HIDP + t] + ((t < HID) ? bias[t] : 0.0f);
    out[c * HIDP + t] = fmaxf(h0, 0.0f);
    if (t < HIDP - 256) {
        int d = 256 + t;
        float h1 = v1 + sn * hw[c * HIDP + d] + ((d < HID) ? bias[d] : 0.0f);
        out[c * HIDP + d] = fmaxf(h1, 0.0f);
    }
}

__global__ void k_colsumA(const float* __restrict__ h, float* __restrict__ g_sum) {
    int r0 = blockIdx.x * 64;
    int t = threadIdx.x;
    float s0 = 0.0f, s1 = 0.0f;
    for (int r = 0; r < 64; ++r) {
        int gr = r0 + r;
        if (gr < N_NODES) {
            s0 += h[gr * HIDP + t];
            if (t < HIDP - 256) s1 += h[gr * HIDP + 256 + t];
        }
    }
    if (t < HID) atomicAdd(&g_sum[t], s0);
    if (t < HIDP - 256 && 256 + t < HID) atomicAdd(&g_sum[256 + t], s1);
}

__global__ void k_head(const float* __restrict__ g_sum,
                       const float* __restrict__ lin1_w, const float* __restrict__ lin1_b,
                       const float* __restrict__ lin2_w, const float* __restrict__ lin2_b,
                       float* __restrict__ out) {
    __shared__ float g2[32];
    int t = threadIdx.x;
    const float inv = 1.0f / (float)N_EDGES;
    if (t < 32) {
        float a = lin1_b[t];
        for (int d = 0; d < HID; ++d) a = fmaf(g_sum[d] * inv, lin1_w[d * 32 + t], a);
        g2[t] = fmaxf(a, 0.0f);
    }
    __syncthreads();
    if (t < 2) {
        float p = lin2_b[t];
        for (int j = 0; j < 32; ++j) p = fmaf(g2[j], lin2_w[j * 2 + t], p);
        out[t] = p;
    }
}

// ---------------------------------------------------------------------------

extern "C" void kernel_launch(void* const* d_in, const int* in_sizes, int n_in,
                              void* d_out, int out_size, void* d_ws, size_t ws_size,
                              hipStream_t stream) {
    (void)in_sizes; (void)n_in; (void)out_size; (void)ws_size;
    const int* edge_index = (const int*)d_in[1];
    const float* edge_attr = (const float*)d_in[2];
    const float* edge_w = (const float*)d_in[6];
    const float* edge_b = (const float*)d_in[7];
    const float* gcn0_w = (const float*)d_in[8];
    const float* gcn0_b = (const float*)d_in[9];
    const float* gcn_w = (const float*)d_in[10];
    const float* gcn_b = (const float*)d_in[11];
    const float* lin1_w = (const float*)d_in[12];
    const float* lin1_b = (const float*)d_in[13];
    const float* lin2_w = (const float*)d_in[14];
    const float* lin2_b = (const float*)d_in[15];

    char* ws = (char*)d_ws;
    size_t off = 0;
    auto alloc = [&](size_t bytes) {
        void* p = ws + off;
        off = (off + bytes + 255) & ~(size_t)255;
        return p;
    };
    float* e_buf = (float*)alloc((size_t)N_EDGES * 32 * 4);
    float* hA = (float*)alloc((size_t)N_NODES * HIDP * 4);
    float* hB = (float*)alloc((size_t)N_NODES * HIDP * 4);
    float* hw = (float*)alloc((size_t)N_NODES * HIDP * 4);
    float* norm = (float*)alloc((size_t)N_EDGES * 4);
    int* edge_sorted = (int*)alloc((size_t)N_EDGES * 4);
    int* cnt = (int*)alloc((size_t)N_NODES * 4);
    int* col_start = (int*)alloc((size_t)(N_NODES + 1) * 4);
    int* cursor = (int*)alloc((size_t)N_NODES * 4);
    float* dinv = (float*)alloc((size_t)N_NODES * 4);
    float* selfnorm = (float*)alloc((size_t)N_NODES * 4);
    float* g_sum = (float*)alloc((size_t)HIDP * 4);
    short* wt0 = (short*)alloc((size_t)38912);
    short* wtl = (short*)alloc((size_t)4 * 389120);
    float* g_part = (float*)alloc((size_t)64 * HIDP * 4);

    const int* row = edge_index;
    const int* col = edge_index + N_EDGES;

    hipMemsetAsync(cnt, 0, N_NODES * 4, stream);
    hipMemsetAsync(g_sum, 0, HIDP * 4, stream);
    hipMemsetAsync(g_part, 0, 64 * HIDP * 4, stream);

    k_edge_embed<<<(N_EDGES * 32 + 255) / 256, 256, 0, stream>>>(edge_attr, edge_w, edge_b, e_buf);
    k_wt<<<(1216 + 48640 + 255) / 256, 256, 0, stream>>>(gcn0_w, gcn_w, wt0, wtl);
    k_count<<<(N_EDGES + 255) / 256, 256, 0, stream>>>(col, cnt);
    k_scan<<<1, 256, 0, stream>>>(cnt, col_start, cursor);
    k_fill<<<(N_EDGES + 255) / 256, 256, 0, stream>>>(col, cursor, edge_sorted);
    k_dinv<<<(N_NODES + 255) / 256, 256, 0, stream>>>(cnt, dinv, selfnorm);
    k_norm<<<(N_EDGES + 255) / 256, 256, 0, stream>>>(row, col, dinv, norm);

    // Part B: split-bf16 MFMA, 32 rows per 64-thread block, no barriers
    k_partB_mfma<<<(NPARTB + 31) / 32, 64, 0, stream>>>(e_buf, wt0, wtl, gcn0_b, gcn_b, g_part);
    k_gsum<<<2, 256, 0, stream>>>(g_part, g_sum);

    // Part A: coupled top-10000 rows, layer by layer
    dim3 gA((N_NODES + 127) / 128, (HIDP + 63) / 64);
    k_gemmA<<<gA, 256, 0, stream>>>(e_buf, 32, 32, 32, gcn0_w, hw);
    k_aggA<<<N_NODES, 256, 0, stream>>>(hw, col_start, edge_sorted, row, norm, selfnorm, gcn0_b, hA);
    float* curr = hA;
    float* next = hB;
    for (int l = 1; l < 5; ++l) {
        k_gemmA<<<gA, 256, 0, stream>>>(curr, HIDP, HIDP, HID, gcn_w + (l - 1) * HID * HID, hw);
        k_aggA<<<N_NODES, 256, 0, stream>>>(hw, col_start, edge_sorted, row, norm, selfnorm,
                                            gcn_b + (l - 1) * HID, next);
        float* tmp = curr; curr = next; next = tmp;
    }
    k_colsumA<<<(N_NODES + 63) / 64, 256, 0, stream>>>(curr, g_sum);
    k_head<<<1, 64, 0, stream>>>(g_sum, lin1_w, lin1_b, lin2_w, lin2_b, (float*)d_out);
}

// Round 3
// 1132.896 us; speedup vs baseline: 2.7251x; 1.3237x over previous
//
#include <hip/hip_runtime.h>
#include <hip/hip_bf16.h>

#define N_NODES 10000
#define N_EDGES 160000
#define HID 300
#define HIDP 304   // padded hidden dim (Part A buffers)
#define NPARTB (N_EDGES - N_NODES)   // 150000 independent rows
#define HSTRIDE 316                  // Part-B LDS row stride (fp32)

typedef __attribute__((ext_vector_type(8))) short short8;
typedef __attribute__((ext_vector_type(4))) float f32x4;

#define MFMA_B16(a, b, c) __builtin_amdgcn_mfma_f32_16x16x32_bf16(a, b, c, 0, 0, 0)

// ---------------------------------------------------------------------------
// small prep kernels
// ---------------------------------------------------------------------------

__global__ void k_edge_embed(const float* __restrict__ edge_attr,
                             const float* __restrict__ edge_w,
                             const float* __restrict__ edge_b,
                             float* __restrict__ e_buf) {
    int idx = blockIdx.x * 256 + threadIdx.x;
    if (idx >= N_EDGES * 32) return;
    int e = idx >> 5, j = idx & 31;
    const float* a = edge_attr + e * 3;
    float v = edge_b[j];
    v = fmaf(a[0], edge_w[j], v);
    v = fmaf(a[1], edge_w[32 + j], v);
    v = fmaf(a[2], edge_w[64 + j], v);
    e_buf[idx] = v;
}

__global__ void k_count(const int* __restrict__ col, int* __restrict__ cnt) {
    int e = blockIdx.x * 256 + threadIdx.x;
    if (e < N_EDGES) atomicAdd(&cnt[col[e]], 1);
}

__global__ void k_scan(const int* __restrict__ cnt, int* __restrict__ col_start,
                       int* __restrict__ cursor) {
    __shared__ int buf[256];
    __shared__ int carry;
    int t = threadIdx.x;
    if (t == 0) carry = 0;
    __syncthreads();
    for (int base = 0; base < N_NODES; base += 256) {
        int i = base + t;
        int v = (i < N_NODES) ? cnt[i] : 0;
        buf[t] = v;
        __syncthreads();
        for (int off = 1; off < 256; off <<= 1) {
            int add = (t >= off) ? buf[t - off] : 0;
            __syncthreads();
            buf[t] += add;
            __syncthreads();
        }
        int excl = buf[t] - v;
        if (i < N_NODES) { col_start[i] = carry + excl; cursor[i] = carry + excl; }
        __syncthreads();
        if (t == 0) carry += buf[255];
        __syncthreads();
    }
    if (t == 0) col_start[N_NODES] = carry;
}

__global__ void k_fill(const int* __restrict__ col, int* __restrict__ cursor,
                       int* __restrict__ edge_sorted) {
    int e = blockIdx.x * 256 + threadIdx.x;
    if (e < N_EDGES) {
        int p = atomicAdd(&cursor[col[e]], 1);
        edge_sorted[p] = e;
    }
}

__global__ void k_dinv(const int* __restrict__ cnt, float* __restrict__ dinv,
                       float* __restrict__ selfnorm) {
    int i = blockIdx.x * 256 + threadIdx.x;
    if (i < N_NODES) {
        float d = (float)cnt[i] + 1.0f;
        dinv[i] = rsqrtf(d);
        selfnorm[i] = 1.0f / d;
    }
}

__global__ void k_norm(const int* __restrict__ row, const int* __restrict__ col,
                       const float* __restrict__ dinv, float* __restrict__ norm) {
    int e = blockIdx.x * 256 + threadIdx.x;
    if (e < N_EDGES) norm[e] = dinv[row[e]] * dinv[col[e]];
}

// ---------------------------------------------------------------------------
// Weight pre-split: fp32 W[k][n] -> bf16 hi/lo in MFMA-B-fragment swizzled
// layout so one wave load = 1 KB contiguous.
// Layer 0 (K=32):  wt0 [nt:19][h:2][q:4][n16:16][j:8] shorts  (38912 B)
// Layers 1-4:      wtl [l:4][chunk:10][nt:19][h:2][q:4][n16:16][j:8]
// ---------------------------------------------------------------------------
__global__ void k_wt(const float* __restrict__ g0w, const float* __restrict__ gw,
                     short* __restrict__ wt0, short* __restrict__ wtl) {
    int idx = blockIdx.x * 256 + threadIdx.x;
    if (idx < 1216) {  // layer 0: 19*4*16 groups
        int n16 = idx & 15, q = (idx >> 4) & 3, nt = idx >> 6;
        int n = nt * 16 + n16;
        short* hd = wt0 + (size_t)(nt * 8 + q) * 128 + n16 * 8;
        short* ld = wt0 + (size_t)(nt * 8 + 4 + q) * 128 + n16 * 8;
#pragma unroll
        for (int j = 0; j < 8; ++j) {
            int k = q * 8 + j;
            float f = (n < HID) ? g0w[k * HID + n] : 0.0f;
            unsigned u = __float_as_uint(f);
            unsigned h = (u + 0x7fffu + ((u >> 16) & 1u)) >> 16;
            float hf = __uint_as_float(h << 16);
            unsigned v = __float_as_uint(f - hf);
            unsigned lo = (v + 0x7fffu + ((v >> 16) & 1u)) >> 16;
            hd[j] = (short)h;
            ld[j] = (short)lo;
        }
    } else if (idx < 1216 + 48640) {
        int i = idx - 1216;
        int n16 = i & 15; i >>= 4;
        int q = i & 3; i >>= 2;
        int nt = i % 19; i /= 19;
        int chunk = i % 10;
        int l = i / 10;
        int n = nt * 16 + n16;
        int cnt_idx = chunk * 19 + nt;
        short* base = wtl + (size_t)l * 194560;
        short* hd = base + (size_t)(cnt_idx * 8 + q) * 128 + n16 * 8;
        short* ld = base + (size_t)(cnt_idx * 8 + 4 + q) * 128 + n16 * 8;
#pragma unroll
        for (int j = 0; j < 8; ++j) {
            int k = chunk * 32 + q * 8 + j;
            float f = (k < HID && n < HID) ? gw[((size_t)l * HID + k) * HID + n] : 0.0f;
            unsigned u = __float_as_uint(f);
            unsigned h = (u + 0x7fffu + ((u >> 16) & 1u)) >> 16;
            float hf = __uint_as_float(h << 16);
            unsigned v = __float_as_uint(f - hf);
            unsigned lo = (v + 0x7fffu + ((v >> 16) & 1u)) >> 16;
            hd[j] = (short)h;
            ld[j] = (short)lo;
        }
    }
}

__device__ __forceinline__ void split8(const float* a, short8& hi, short8& lo) {
#pragma unroll
    for (int j = 0; j < 8; ++j) {
        float x = a[j];
        unsigned u = __float_as_uint(x);
        unsigned h = (u + 0x7fffu + ((u >> 16) & 1u)) >> 16;
        float hf = __uint_as_float(h << 16);
        float d = x - hf;
        unsigned v = __float_as_uint(d);
        unsigned l = (v + 0x7fffu + ((v >> 16) & 1u)) >> 16;
        hi[j] = (short)h;
        lo[j] = (short)l;
    }
}

// ---------------------------------------------------------------------------
// Part B (MFMA): 1 wave per block, 32 rows/wave, H fp32 in LDS.
// Chunk-batched B loads: all 38 dwordx4 B-fragment loads issued before the
// MFMA burst (152 VGPRs of in-flight data; 1 wave/SIMD so regs are free) —
// converts the latency-bound nt-loop into an L2-BW-bound stream.
// ---------------------------------------------------------------------------
__global__ __launch_bounds__(64, 1) void k_partB_mfma(
    const float* __restrict__ e_buf,
    const short* __restrict__ wt0,
    const short* __restrict__ wtl,
    const float* __restrict__ b0,
    const float* __restrict__ gb,
    float* __restrict__ g_part) {
    __shared__ float H[32 * HSTRIDE];   // 40448 B -> 4 blocks/CU
    int lane = threadIdx.x;
    int l16 = lane & 15;
    int quad = lane >> 4;
    int base = N_NODES + blockIdx.x * 32;

    f32x4 acc[2][19];
    short8 ahi[2], alo[2];
    short8 bh[19], bl[19];

    // ---------------- layer 0 (K=32) ----------------
#pragma unroll
    for (int nt = 0; nt < 19; ++nt) {
        const short* p = wt0 + (size_t)nt * 1024 + quad * 128 + l16 * 8;
        bh[nt] = *(const short8*)p;
        bl[nt] = *(const short8*)(p + 512);
    }
#pragma unroll
    for (int mt = 0; mt < 2; ++mt) {
        int gr = base + mt * 16 + l16;
        float a8[8];
        if (gr < N_EDGES) {
            float4 t0 = *(const float4*)(e_buf + (size_t)gr * 32 + quad * 8);
            float4 t1 = *(const float4*)(e_buf + (size_t)gr * 32 + quad * 8 + 4);
            a8[0] = t0.x; a8[1] = t0.y; a8[2] = t0.z; a8[3] = t0.w;
            a8[4] = t1.x; a8[5] = t1.y; a8[6] = t1.z; a8[7] = t1.w;
        } else {
#pragma unroll
            for (int j = 0; j < 8; ++j) a8[j] = 0.0f;
        }
        split8(a8, ahi[mt], alo[mt]);
    }
#pragma unroll
    for (int mt = 0; mt < 2; ++mt)
#pragma unroll
        for (int nt = 0; nt < 19; ++nt)
#pragma unroll
            for (int r = 0; r < 4; ++r) acc[mt][nt][r] = 0.0f;
#pragma unroll
    for (int nt = 0; nt < 19; ++nt) {
        acc[0][nt] = MFMA_B16(ahi[0], bh[nt], acc[0][nt]);
        acc[0][nt] = MFMA_B16(ahi[0], bl[nt], acc[0][nt]);
        acc[0][nt] = MFMA_B16(alo[0], bh[nt], acc[0][nt]);
        acc[1][nt] = MFMA_B16(ahi[1], bh[nt], acc[1][nt]);
        acc[1][nt] = MFMA_B16(ahi[1], bl[nt], acc[1][nt]);
        acc[1][nt] = MFMA_B16(alo[1], bh[nt], acc[1][nt]);
    }
#pragma unroll
    for (int nt = 0; nt < 19; ++nt) {
        int c = nt * 16 + l16;
        float b = (c < HID) ? b0[c] : 0.0f;
#pragma unroll
        for (int mt = 0; mt < 2; ++mt)
#pragma unroll
            for (int r = 0; r < 4; ++r)
                H[(mt * 16 + quad * 4 + r) * HSTRIDE + c] =
                    fmaxf(acc[mt][nt][r] + b, 0.0f);
    }

    // ---------------- layers 1..4 (K=304, 10 chunks, chunk 9 half-masked) ---
    for (int l = 0; l < 4; ++l) {
        const short* wl = wtl + (size_t)l * 194560;
        const float* bias = gb + l * HID;
#pragma unroll
        for (int mt = 0; mt < 2; ++mt)
#pragma unroll
            for (int nt = 0; nt < 19; ++nt)
#pragma unroll
                for (int r = 0; r < 4; ++r) acc[mt][nt][r] = 0.0f;

        for (int chunk = 0; chunk < 10; ++chunk) {
            const short* cbase = wl + (size_t)(chunk * 19) * 1024 + quad * 128 + l16 * 8;
#pragma unroll
            for (int nt = 0; nt < 19; ++nt) {
                const short* p = cbase + (size_t)nt * 1024;
                bh[nt] = *(const short8*)p;
                bl[nt] = *(const short8*)(p + 512);
            }
            bool dead = (chunk == 9) && (quad >= 2);
            int kb = dead ? 288 : (chunk * 32 + quad * 8);
#pragma unroll
            for (int mt = 0; mt < 2; ++mt) {
                const float* hp = &H[(mt * 16 + l16) * HSTRIDE + kb];
                float4 t0 = *(const float4*)hp;
                float4 t1 = *(const float4*)(hp + 4);
                float a8[8] = {t0.x, t0.y, t0.z, t0.w, t1.x, t1.y, t1.z, t1.w};
                split8(a8, ahi[mt], alo[mt]);
                if (dead) {
#pragma unroll
                    for (int j = 0; j < 8; ++j) { ahi[mt][j] = 0; alo[mt][j] = 0; }
                }
            }
#pragma unroll
            for (int nt = 0; nt < 19; ++nt) {
                acc[0][nt] = MFMA_B16(ahi[0], bh[nt], acc[0][nt]);
                acc[0][nt] = MFMA_B16(ahi[0], bl[nt], acc[0][nt]);
                acc[0][nt] = MFMA_B16(alo[0], bh[nt], acc[0][nt]);
                acc[1][nt] = MFMA_B16(ahi[1], bh[nt], acc[1][nt]);
                acc[1][nt] = MFMA_B16(ahi[1], bl[nt], acc[1][nt]);
                acc[1][nt] = MFMA_B16(alo[1], bh[nt], acc[1][nt]);
            }
        }

        if (l < 3) {
#pragma unroll
            for (int nt = 0; nt < 19; ++nt) {
                int c = nt * 16 + l16;
                float b = (c < HID) ? bias[c] : 0.0f;
#pragma unroll
                for (int mt = 0; mt < 2; ++mt)
#pragma unroll
                    for (int r = 0; r < 4; ++r)
                        H[(mt * 16 + quad * 4 + r) * HSTRIDE + c] =
                            fmaxf(acc[mt][nt][r] + b, 0.0f);
            }
        } else {
            int valid = N_EDGES - base;
            if (valid > 32) valid = 32;
#pragma unroll
            for (int nt = 0; nt < 19; ++nt) {
                int c = nt * 16 + l16;
                float b = (c < HID) ? bias[c] : 0.0f;
                float s = 0.0f;
#pragma unroll
                for (int mt = 0; mt < 2; ++mt)
#pragma unroll
                    for (int r = 0; r < 4; ++r) {
                        int rr = mt * 16 + quad * 4 + r;
                        float v = fmaxf(acc[mt][nt][r] + b, 0.0f);
                        if (rr < valid) s += v;
                    }
                s += __shfl_xor(s, 16, 64);
                s += __shfl_xor(s, 32, 64);
                if (quad == 0 && c < HID)
                    atomicAdd(&g_part[(blockIdx.x & 63) * HIDP + c], s);
            }
        }
    }
}

__global__ void k_gsum(const float* __restrict__ g_part, float* __restrict__ g_sum) {
    int c = blockIdx.x * 256 + threadIdx.x;
    if (c < HID) {
        float s = 0.0f;
        for (int g = 0; g < 64; ++g) s += g_part[g * HIDP + c];
        atomicAdd(&g_sum[c], s);
    }
}

// ---------------------------------------------------------------------------
// Part A GEMM (MFMA): HW[10000][304] = split-bf16( A[10000][lda] ) @ wt
// Same batched-load inner loop as Part B; raw accumulator out (no epilogue).
// nchunks==1 -> layer 0 (wt0, K=32); nchunks==10 -> hidden layer (K=304).
// ---------------------------------------------------------------------------
__global__ __launch_bounds__(64, 1) void k_gemmA_mfma(
    const float* __restrict__ A, int lda, int nchunks,
    const short* __restrict__ wt,
    float* __restrict__ HW) {
    int lane = threadIdx.x;
    int l16 = lane & 15;
    int quad = lane >> 4;
    int base = blockIdx.x * 32;

    f32x4 acc[2][19];
    short8 ahi[2], alo[2];
    short8 bh[19], bl[19];
#pragma unroll
    for (int mt = 0; mt < 2; ++mt)
#pragma unroll
        for (int nt = 0; nt < 19; ++nt)
#pragma unroll
            for (int r = 0; r < 4; ++r) acc[mt][nt][r] = 0.0f;

    for (int chunk = 0; chunk < nchunks; ++chunk) {
        const short* cbase = wt + (size_t)(chunk * 19) * 1024 + quad * 128 + l16 * 8;
#pragma unroll
        for (int nt = 0; nt < 19; ++nt) {
            const short* p = cbase + (size_t)nt * 1024;
            bh[nt] = *(const short8*)p;
            bl[nt] = *(const short8*)(p + 512);
        }
        bool dead = (nchunks == 10) && (chunk == 9) && (quad >= 2);
        int kb = chunk * 32 + quad * 8;
#pragma unroll
        for (int mt = 0; mt < 2; ++mt) {
            int gr = base + mt * 16 + l16;
            float a8[8];
            if (gr < N_NODES && !dead) {
                const float* ap = A + (size_t)gr * lda + kb;
                float4 t0 = *(const float4*)ap;
                float4 t1 = *(const float4*)(ap + 4);
                a8[0] = t0.x; a8[1] = t0.y; a8[2] = t0.z; a8[3] = t0.w;
                a8[4] = t1.x; a8[5] = t1.y; a8[6] = t1.z; a8[7] = t1.w;
            } else {
#pragma unroll
                for (int j = 0; j < 8; ++j) a8[j] = 0.0f;
            }
            split8(a8, ahi[mt], alo[mt]);
        }
#pragma unroll
        for (int nt = 0; nt < 19; ++nt) {
            acc[0][nt] = MFMA_B16(ahi[0], bh[nt], acc[0][nt]);
            acc[0][nt] = MFMA_B16(ahi[0], bl[nt], acc[0][nt]);
            acc[0][nt] = MFMA_B16(alo[0], bh[nt], acc[0][nt]);
            acc[1][nt] = MFMA_B16(ahi[1], bh[nt], acc[1][nt]);
            acc[1][nt] = MFMA_B16(ahi[1], bl[nt], acc[1][nt]);
            acc[1][nt] = MFMA_B16(alo[1], bh[nt], acc[1][nt]);
        }
    }
#pragma unroll
    for (int nt = 0; nt < 19; ++nt) {
        int c = nt * 16 + l16;
#pragma unroll
        for (int mt = 0; mt < 2; ++mt)
#pragma unroll
            for (int r = 0; r < 4; ++r) {
                int gm = base + mt * 16 + quad * 4 + r;
                if (gm < N_NODES) HW[(size_t)gm * HIDP + c] = acc[mt][nt][r];
            }
    }
}

// ---------------------------------------------------------------------------
// Part A aggregation: one WAVE per destination node (4 nodes / 256-thr block,
// no LDS, no barriers). Lane j covers cols {lane, lane+64, ..., lane+256}.
// ---------------------------------------------------------------------------
__global__ __launch_bounds__(256) void k_aggA(
    const float* __restrict__ hw, const int* __restrict__ col_start,
    const int* __restrict__ edge_sorted, const int* __restrict__ row,
    const float* __restrict__ norm, const float* __restrict__ selfnorm,
    const float* __restrict__ bias, float* __restrict__ out) {
    int wid = (blockIdx.x * 256 + threadIdx.x) >> 6;
    int lane = threadIdx.x & 63;
    if (wid >= N_NODES) return;
    int c = wid;
    int beg = col_start[c], end = col_start[c + 1];
    float v[5];
#pragma unroll
    for (int j = 0; j < 5; ++j) v[j] = 0.0f;
    for (int b = beg; b < end; b += 64) {
        int eidx = b + lane;
        int rr = 0;
        float nn = 0.0f;
        if (eidx < end) {
            int e = edge_sorted[eidx];
            rr = row[e];
            nn = norm[e];
        }
        int m = min(64, end - b);
        for (int i = 0; i < m; ++i) {
            int r2 = __shfl(rr, i, 64);
            float n2 = __shfl(nn, i, 64);
            const float* hp = hw + (size_t)r2 * HIDP;
#pragma unroll
            for (int j = 0; j < 5; ++j) {
                int col = lane + 64 * j;
                if (col < HIDP) v[j] = fmaf(n2, hp[col], v[j]);
            }
        }
    }
    float sn = selfnorm[c];
    const float* sp = hw + (size_t)c * HIDP;
#pragma unroll
    for (int j = 0; j < 5; ++j) {
        int col = lane + 64 * j;
        if (col < HIDP) {
            float h = v[j] + sn * sp[col] + ((col < HID) ? bias[col] : 0.0f);
            out[(size_t)c * HIDP + col] = fmaxf(h, 0.0f);
        }
    }
}

__global__ void k_colsumA(const float* __restrict__ h, float* __restrict__ g_sum) {
    int r0 = blockIdx.x * 64;
    int t = threadIdx.x;
    float s0 = 0.0f, s1 = 0.0f;
    for (int r = 0; r < 64; ++r) {
        int gr = r0 + r;
        if (gr < N_NODES) {
            s0 += h[gr * HIDP + t];
            if (t < HIDP - 256) s1 += h[gr * HIDP + 256 + t];
        }
    }
    if (t < HID) atomicAdd(&g_sum[t], s0);
    if (t < HIDP - 256 && 256 + t < HID) atomicAdd(&g_sum[256 + t], s1);
}

__global__ void k_head(const float* __restrict__ g_sum,
                       const float* __restrict__ lin1_w, const float* __restrict__ lin1_b,
                       const float* __restrict__ lin2_w, const float* __restrict__ lin2_b,
                       float* __restrict__ out) {
    __shared__ float g2[32];
    int t = threadIdx.x;
    const float inv = 1.0f / (float)N_EDGES;
    if (t < 32) {
        float a = lin1_b[t];
        for (int d = 0; d < HID; ++d) a = fmaf(g_sum[d] * inv, lin1_w[d * 32 + t], a);
        g2[t] = fmaxf(a, 0.0f);
    }
    __syncthreads();
    if (t < 2) {
        float p = lin2_b[t];
        for (int j = 0; j < 32; ++j) p = fmaf(g2[j], lin2_w[j * 2 + t], p);
        out[t] = p;
    }
}

// ---------------------------------------------------------------------------

extern "C" void kernel_launch(void* const* d_in, const int* in_sizes, int n_in,
                              void* d_out, int out_size, void* d_ws, size_t ws_size,
                              hipStream_t stream) {
    (void)in_sizes; (void)n_in; (void)out_size; (void)ws_size;
    const int* edge_index = (const int*)d_in[1];
    const float* edge_attr = (const float*)d_in[2];
    const float* edge_w = (const float*)d_in[6];
    const float* edge_b = (const float*)d_in[7];
    const float* gcn0_w = (const float*)d_in[8];
    const float* gcn0_b = (const float*)d_in[9];
    const float* gcn_w = (const float*)d_in[10];
    const float* gcn_b = (const float*)d_in[11];
    const float* lin1_w = (const float*)d_in[12];
    const float* lin1_b = (const float*)d_in[13];
    const float* lin2_w = (const float*)d_in[14];
    const float* lin2_b = (const float*)d_in[15];

    char* ws = (char*)d_ws;
    size_t off = 0;
    auto alloc = [&](size_t bytes) {
        void* p = ws + off;
        off = (off + bytes + 255) & ~(size_t)255;
        return p;
    };
    float* e_buf = (float*)alloc((size_t)N_EDGES * 32 * 4);
    float* hA = (float*)alloc((size_t)N_NODES * HIDP * 4);
    float* hB = (float*)alloc((size_t)N_NODES * HIDP * 4);
    float* hw = (float*)alloc((size_t)N_NODES * HIDP * 4);
    float* norm = (float*)alloc((size_t)N_EDGES * 4);
    int* edge_sorted = (int*)alloc((size_t)N_EDGES * 4);
    int* cnt = (int*)alloc((size_t)N_NODES * 4);
    int* col_start = (int*)alloc((size_t)(N_NODES + 1) * 4);
    int* cursor = (int*)alloc((size_t)N_NODES * 4);
    float* dinv = (float*)alloc((size_t)N_NODES * 4);
    float* selfnorm = (float*)alloc((size_t)N_NODES * 4);
    float* g_sum = (float*)alloc((size_t)HIDP * 4);
    short* wt0 = (short*)alloc((size_t)38912);
    short* wtl = (short*)alloc((size_t)4 * 389120);
    float* g_part = (float*)alloc((size_t)64 * HIDP * 4);

    const int* row = edge_index;
    const int* col = edge_index + N_EDGES;

    hipMemsetAsync(cnt, 0, N_NODES * 4, stream);
    hipMemsetAsync(g_sum, 0, HIDP * 4, stream);
    hipMemsetAsync(g_part, 0, 64 * HIDP * 4, stream);

    k_edge_embed<<<(N_EDGES * 32 + 255) / 256, 256, 0, stream>>>(edge_attr, edge_w, edge_b, e_buf);
    k_wt<<<(1216 + 48640 + 255) / 256, 256, 0, stream>>>(gcn0_w, gcn_w, wt0, wtl);
    k_count<<<(N_EDGES + 255) / 256, 256, 0, stream>>>(col, cnt);
    k_scan<<<1, 256, 0, stream>>>(cnt, col_start, cursor);
    k_fill<<<(N_EDGES + 255) / 256, 256, 0, stream>>>(col, cursor, edge_sorted);
    k_dinv<<<(N_NODES + 255) / 256, 256, 0, stream>>>(cnt, dinv, selfnorm);
    k_norm<<<(N_EDGES + 255) / 256, 256, 0, stream>>>(row, col, dinv, norm);

    // Part B: split-bf16 MFMA, chunk-batched B loads
    k_partB_mfma<<<(NPARTB + 31) / 32, 64, 0, stream>>>(e_buf, wt0, wtl, gcn0_b, gcn_b, g_part);
    k_gsum<<<2, 256, 0, stream>>>(g_part, g_sum);

    // Part A: coupled top-10000 rows, layer by layer (MFMA GEMM + wave-per-node agg)
    const int gemmA_blocks = (N_NODES + 31) / 32;
    const int aggA_blocks = (N_NODES + 3) / 4;
    k_gemmA_mfma<<<gemmA_blocks, 64, 0, stream>>>(e_buf, 32, 1, wt0, hw);
    k_aggA<<<aggA_blocks, 256, 0, stream>>>(hw, col_start, edge_sorted, row, norm, selfnorm, gcn0_b, hA);
    float* curr = hA;
    float* next = hB;
    for (int l = 1; l < 5; ++l) {
        k_gemmA_mfma<<<gemmA_blocks, 64, 0, stream>>>(curr, HIDP, 10, wtl + (size_t)(l - 1) * 194560, hw);
        k_aggA<<<aggA_blocks, 256, 0, stream>>>(hw, col_start, edge_sorted, row, norm, selfnorm,
                                                gcn_b + (l - 1) * HID, next);
        float* tmp = curr; curr = next; next = tmp;
    }
    k_colsumA<<<(N_NODES + 63) / 64, 256, 0, stream>>>(curr, g_sum);
    k_head<<<1, 64, 0, stream>>>(g_sum, lin1_w, lin1_b, lin2_w, lin2_b, (float*)d_out);
}

// Round 4
// 730.968 us; speedup vs baseline: 4.2235x; 1.5499x over previous
//
#include <hip/hip_runtime.h>
#include <hip/hip_bf16.h>

#define N_NODES 10000
#define N_EDGES 160000
#define HID 300
#define HIDP 304   // padded hidden dim (Part A buffers)
#define NPARTB (N_EDGES - N_NODES)   // 150000 independent rows
#define RB 48      // rows per GCN block (3 M-tiles)
#define KS 328     // H-plane k-stride in shorts (656B rows -> 2-way banks, free)

typedef __attribute__((ext_vector_type(8))) short short8;
typedef __attribute__((ext_vector_type(4))) float f32x4;

#define MFMA_B16(a, b, c) __builtin_amdgcn_mfma_f32_16x16x32_bf16(a, b, c, 0, 0, 0)

__device__ __forceinline__ void split1(float x, short& hi, short& lo) {
    unsigned u = __float_as_uint(x);
    unsigned h = (u + 0x7fffu + ((u >> 16) & 1u)) >> 16;
    float hf = __uint_as_float(h << 16);
    float d = x - hf;
    unsigned v = __float_as_uint(d);
    unsigned l = (v + 0x7fffu + ((v >> 16) & 1u)) >> 16;
    hi = (short)h;
    lo = (short)l;
}

// ---------------------------------------------------------------------------
// small prep kernels
// ---------------------------------------------------------------------------

__global__ void k_edge_embed(const float* __restrict__ edge_attr,
                             const float* __restrict__ edge_w,
                             const float* __restrict__ edge_b,
                             float* __restrict__ e_buf) {
    int idx = blockIdx.x * 256 + threadIdx.x;
    if (idx >= N_EDGES * 32) return;
    int e = idx >> 5, j = idx & 31;
    const float* a = edge_attr + e * 3;
    float v = edge_b[j];
    v = fmaf(a[0], edge_w[j], v);
    v = fmaf(a[1], edge_w[32 + j], v);
    v = fmaf(a[2], edge_w[64 + j], v);
    e_buf[idx] = v;
}

__global__ void k_count(const int* __restrict__ col, int* __restrict__ cnt) {
    int e = blockIdx.x * 256 + threadIdx.x;
    if (e < N_EDGES) atomicAdd(&cnt[col[e]], 1);
}

// shfl-based scan over 10000 counts; also emits dinv/selfnorm (k_dinv folded in)
__global__ void k_scan(const int* __restrict__ cnt, int* __restrict__ col_start,
                       int* __restrict__ cursor, float* __restrict__ dinv,
                       float* __restrict__ selfnorm) {
    __shared__ int wsum[4];
    int t = threadIdx.x;
    int lane = t & 63, w = t >> 6;
    int carry = 0;
    for (int base = 0; base < N_NODES; base += 256) {
        int i = base + t;
        int v = (i < N_NODES) ? cnt[i] : 0;
        int s = v;
#pragma unroll
        for (int d = 1; d < 64; d <<= 1) {
            int n = __shfl_up(s, d, 64);
            if (lane >= d) s += n;
        }
        if (lane == 63) wsum[w] = s;
        __syncthreads();
        int woff = 0;
#pragma unroll
        for (int k = 0; k < 4; ++k)
            if (k < w) woff += wsum[k];
        int total = wsum[0] + wsum[1] + wsum[2] + wsum[3];
        if (i < N_NODES) {
            int excl = carry + woff + s - v;
            col_start[i] = excl;
            cursor[i] = excl;
            float dd = (float)v + 1.0f;
            dinv[i] = rsqrtf(dd);
            selfnorm[i] = 1.0f / dd;
        }
        carry += total;
        __syncthreads();
    }
    if (t == 0) col_start[N_NODES] = carry;
}

// fill CSR with (row, norm) packed directly (saves an indirection in aggA)
__global__ void k_fill(const int* __restrict__ row, const int* __restrict__ col,
                       int* __restrict__ cursor, const float* __restrict__ dinv,
                       int* __restrict__ row_sorted, float* __restrict__ norm_sorted) {
    int e = blockIdx.x * 256 + threadIdx.x;
    if (e < N_EDGES) {
        int c = col[e], r = row[e];
        int p = atomicAdd(&cursor[c], 1);
        row_sorted[p] = r;
        norm_sorted[p] = dinv[r] * dinv[c];
    }
}

// ---------------------------------------------------------------------------
// Weight pre-split (unchanged layout from R2/R3 — verified):
// wt0 [nt:19][h:2][q:4][n16:16][j:8] shorts; wtl [l:4][chunk:10][nt:19][...]
// ---------------------------------------------------------------------------
__global__ void k_wt(const float* __restrict__ g0w, const float* __restrict__ gw,
                     short* __restrict__ wt0, short* __restrict__ wtl) {
    int idx = blockIdx.x * 256 + threadIdx.x;
    if (idx < 1216) {
        int n16 = idx & 15, q = (idx >> 4) & 3, nt = idx >> 6;
        int n = nt * 16 + n16;
        short* hd = wt0 + (size_t)(nt * 8 + q) * 128 + n16 * 8;
        short* ld = wt0 + (size_t)(nt * 8 + 4 + q) * 128 + n16 * 8;
#pragma unroll
        for (int j = 0; j < 8; ++j) {
            int k = q * 8 + j;
            float f = (n < HID) ? g0w[k * HID + n] : 0.0f;
            short hi, lo;
            split1(f, hi, lo);
            hd[j] = hi;
            ld[j] = lo;
        }
    } else if (idx < 1216 + 48640) {
        int i = idx - 1216;
        int n16 = i & 15; i >>= 4;
        int q = i & 3; i >>= 2;
        int nt = i % 19; i /= 19;
        int chunk = i % 10;
        int l = i / 10;
        int n = nt * 16 + n16;
        int cnt_idx = chunk * 19 + nt;
        short* base = wtl + (size_t)l * 194560;
        short* hd = base + (size_t)(cnt_idx * 8 + q) * 128 + n16 * 8;
        short* ld = base + (size_t)(cnt_idx * 8 + 4 + q) * 128 + n16 * 8;
#pragma unroll
        for (int j = 0; j < 8; ++j) {
            int k = chunk * 32 + q * 8 + j;
            float f = (k < HID && n < HID) ? gw[((size_t)l * HID + k) * HID + n] : 0.0f;
            short hi, lo;
            split1(f, hi, lo);
            hd[j] = hi;
            ld[j] = lo;
        }
    }
}

// ---------------------------------------------------------------------------
// Shared GCN building blocks. Block = 8 waves, 48 rows; H pre-split in LDS
// planes (hi/lo shorts). Wave w owns NTC n-tiles starting at nt0.
// k-loop: zero VALU — 2 ds_read_b128 per M-tile + raw MFMA.
// ---------------------------------------------------------------------------

template <int NTC>
__device__ __forceinline__ void gcn_kloop(const short* __restrict__ wp, int nchunks,
                                          const short* Hh, const short* Hl,
                                          int nt0, int quad, int l16,
                                          f32x4 (&acc)[3][3]) {
#pragma unroll
    for (int mt = 0; mt < 3; ++mt)
#pragma unroll
        for (int i = 0; i < NTC; ++i)
#pragma unroll
            for (int r = 0; r < 4; ++r) acc[mt][i][r] = 0.0f;
    for (int chunk = 0; chunk < nchunks; ++chunk) {
        short8 bh[NTC], bl[NTC], ah[3], al[3];
        const short* cb = wp + (size_t)(chunk * 19 + nt0) * 1024 + quad * 128 + l16 * 8;
#pragma unroll
        for (int i = 0; i < NTC; ++i) {
            bh[i] = *(const short8*)(cb + (size_t)i * 1024);
            bl[i] = *(const short8*)(cb + (size_t)i * 1024 + 512);
        }
        int kb = chunk * 32 + quad * 8;
#pragma unroll
        for (int mt = 0; mt < 3; ++mt) {
            int off = (mt * 16 + l16) * KS + kb;
            ah[mt] = *(const short8*)&Hh[off];
            al[mt] = *(const short8*)&Hl[off];
        }
#pragma unroll
        for (int mt = 0; mt < 3; ++mt)
#pragma unroll
            for (int i = 0; i < NTC; ++i) {
                acc[mt][i] = MFMA_B16(ah[mt], bh[i], acc[mt][i]);
                acc[mt][i] = MFMA_B16(ah[mt], bl[i], acc[mt][i]);
                acc[mt][i] = MFMA_B16(al[mt], bh[i], acc[mt][i]);
            }
    }
}

template <int NTC>
__device__ __forceinline__ void gcn_epilogue(const float* __restrict__ bias,
                                             int nt0, int quad, int l16,
                                             f32x4 (&acc)[3][3],
                                             short* Hh, short* Hl) {
#pragma unroll
    for (int i = 0; i < NTC; ++i) {
        int c = (nt0 + i) * 16 + l16;
        float b = (c < HID) ? bias[c] : 0.0f;
#pragma unroll
        for (int mt = 0; mt < 3; ++mt)
#pragma unroll
            for (int r = 0; r < 4; ++r) {
                float v = fmaxf(acc[mt][i][r] + b, 0.0f);
                short hi, lo;
                split1(v, hi, lo);
                int off = (mt * 16 + quad * 4 + r) * KS + c;
                Hh[off] = hi;
                Hl[off] = lo;
            }
    }
}

template <int NTC>
__device__ __forceinline__ void gcn_final(const float* __restrict__ bias,
                                          int nt0, int quad, int l16, int slot,
                                          f32x4 (&acc)[3][3],
                                          float* __restrict__ g_part) {
#pragma unroll
    for (int i = 0; i < NTC; ++i) {
        int c = (nt0 + i) * 16 + l16;
        float b = (c < HID) ? bias[c] : 0.0f;
        float s = 0.0f;
#pragma unroll
        for (int mt = 0; mt < 3; ++mt)
#pragma unroll
            for (int r = 0; r < 4; ++r) s += fmaxf(acc[mt][i][r] + b, 0.0f);
        s += __shfl_xor(s, 16, 64);
        s += __shfl_xor(s, 32, 64);
        if (quad == 0 && c < HID)
            atomicAdd(&g_part[slot * HIDP + c], s);
    }
}

// ---------------------------------------------------------------------------
// Part B: fused 5-layer, 48 rows/block (exactly 3125 blocks, no tail).
// ---------------------------------------------------------------------------
__global__ __launch_bounds__(512, 4) void k_partB_mfma(
    const float* __restrict__ e_buf,
    const short* __restrict__ wt0,
    const short* __restrict__ wtl,
    const float* __restrict__ b0,
    const float* __restrict__ gb,
    float* __restrict__ g_part) {
    __shared__ short Hh[RB * KS];
    __shared__ short Hl[RB * KS];
    int t = threadIdx.x;
    int lane = t & 63, w = t >> 6;
    int l16 = lane & 15, quad = lane >> 4;
    int base = N_NODES + blockIdx.x * RB;
    int nt0 = (w < 3) ? w * 3 : 9 + (w - 3) * 2;

    // stage layer-0 input (48 x 32), split once
    if (t < 384) {
        int r = t >> 3, c4 = (t & 7) * 4;
        float4 v = *(const float4*)(e_buf + (size_t)(base + r) * 32 + c4);
        float a4[4] = {v.x, v.y, v.z, v.w};
#pragma unroll
        for (int j = 0; j < 4; ++j) {
            short hi, lo;
            split1(a4[j], hi, lo);
            Hh[r * KS + c4 + j] = hi;
            Hl[r * KS + c4 + j] = lo;
        }
    }
    // zero pad cols [304,328) once — padded-zero weights then hit clean zeros
    for (int i = t; i < RB * 24; i += 512) {
        int r = i / 24, k = 304 + i % 24;
        Hh[r * KS + k] = 0;
        Hl[r * KS + k] = 0;
    }
    __syncthreads();

    f32x4 acc[3][3];
    for (int layer = 0; layer < 5; ++layer) {
        const short* wp = (layer == 0) ? wt0 : wtl + (size_t)(layer - 1) * 194560;
        const float* bias = (layer == 0) ? b0 : gb + (layer - 1) * HID;
        int nch = (layer == 0) ? 1 : 10;
        if (w < 3) gcn_kloop<3>(wp, nch, Hh, Hl, nt0, quad, l16, acc);
        else       gcn_kloop<2>(wp, nch, Hh, Hl, nt0, quad, l16, acc);
        __syncthreads();   // all H reads done before overwrite
        if (layer < 4) {
            if (w < 3) gcn_epilogue<3>(bias, nt0, quad, l16, acc, Hh, Hl);
            else       gcn_epilogue<2>(bias, nt0, quad, l16, acc, Hh, Hl);
            __syncthreads();
        } else {
            int slot = (blockIdx.x + w) & 63;
            if (w < 3) gcn_final<3>(bias, nt0, quad, l16, slot, acc, g_part);
            else       gcn_final<2>(bias, nt0, quad, l16, slot, acc, g_part);
        }
    }
}

__global__ void k_gsum(const float* __restrict__ g_part, float* __restrict__ g_sum) {
    int c = blockIdx.x * 256 + threadIdx.x;
    if (c < HID) {
        float s = 0.0f;
        for (int g = 0; g < 64; ++g) s += g_part[g * HIDP + c];
        atomicAdd(&g_sum[c], s);
    }
}

// ---------------------------------------------------------------------------
// Part A GEMM: same structure, single layer, raw fp32 out.
// ---------------------------------------------------------------------------
template <int NTC>
__device__ __forceinline__ void gemm_out(int base, int nt0, int quad, int l16,
                                         f32x4 (&acc)[3][3], float* __restrict__ HW) {
#pragma unroll
    for (int i = 0; i < NTC; ++i) {
        int c = (nt0 + i) * 16 + l16;
#pragma unroll
        for (int mt = 0; mt < 3; ++mt)
#pragma unroll
            for (int r = 0; r < 4; ++r) {
                int gm = base + mt * 16 + quad * 4 + r;
                if (gm < N_NODES) HW[(size_t)gm * HIDP + c] = acc[mt][i][r];
            }
    }
}

__global__ __launch_bounds__(512, 4) void k_gemmA(
    const float* __restrict__ A, int lda, int ncols, int nchunks,
    const short* __restrict__ wt, float* __restrict__ HW) {
    __shared__ short Hh[RB * KS];
    __shared__ short Hl[RB * KS];
    int t = threadIdx.x;
    int lane = t & 63, w = t >> 6;
    int l16 = lane & 15, quad = lane >> 4;
    int base = blockIdx.x * RB;
    int nt0 = (w < 3) ? w * 3 : 9 + (w - 3) * 2;

    int nc4 = ncols >> 2;
    for (int idx = t; idx < RB * nc4; idx += 512) {
        int r = idx / nc4, c4 = (idx % nc4) * 4;
        int gr = base + r;
        float a4[4] = {0.0f, 0.0f, 0.0f, 0.0f};
        if (gr < N_NODES) {
            float4 v = *(const float4*)(A + (size_t)gr * lda + c4);
            a4[0] = v.x; a4[1] = v.y; a4[2] = v.z; a4[3] = v.w;
        }
#pragma unroll
        for (int j = 0; j < 4; ++j) {
            short hi, lo;
            split1(a4[j], hi, lo);
            Hh[r * KS + c4 + j] = hi;
            Hl[r * KS + c4 + j] = lo;
        }
    }
    if (ncols > 32) {
        for (int i = t; i < RB * 24; i += 512) {
            int r = i / 24, k = 304 + i % 24;
            Hh[r * KS + k] = 0;
            Hl[r * KS + k] = 0;
        }
    }
    __syncthreads();

    f32x4 acc[3][3];
    if (w < 3) gcn_kloop<3>(wt, nchunks, Hh, Hl, nt0, quad, l16, acc);
    else       gcn_kloop<2>(wt, nchunks, Hh, Hl, nt0, quad, l16, acc);
    if (w < 3) gemm_out<3>(base, nt0, quad, l16, acc, HW);
    else       gemm_out<2>(base, nt0, quad, l16, acc, HW);
}

// ---------------------------------------------------------------------------
// Part A aggregation: one wave per destination node; CSR holds (row, norm).
// ---------------------------------------------------------------------------
__global__ __launch_bounds__(256) void k_aggA(
    const float* __restrict__ hw, const int* __restrict__ col_start,
    const int* __restrict__ row_sorted, const float* __restrict__ norm_sorted,
    const float* __restrict__ selfnorm,
    const float* __restrict__ bias, float* __restrict__ out) {
    int wid = (blockIdx.x * 256 + threadIdx.x) >> 6;
    int lane = threadIdx.x & 63;
    if (wid >= N_NODES) return;
    int c = wid;
    int beg = col_start[c], end = col_start[c + 1];
    float v[5];
#pragma unroll
    for (int j = 0; j < 5; ++j) v[j] = 0.0f;
    for (int b = beg; b < end; b += 64) {
        int eidx = b + lane;
        int rr = 0;
        float nn = 0.0f;
        if (eidx < end) {
            rr = row_sorted[eidx];
            nn = norm_sorted[eidx];
        }
        int m = min(64, end - b);
        for (int i = 0; i < m; ++i) {
            int r2 = __shfl(rr, i, 64);
            float n2 = __shfl(nn, i, 64);
            const float* hp = hw + (size_t)r2 * HIDP;
#pragma unroll
            for (int j = 0; j < 5; ++j) {
                int col = lane + 64 * j;
                if (col < HIDP) v[j] = fmaf(n2, hp[col], v[j]);
            }
        }
    }
    float sn = selfnorm[c];
    const float* sp = hw + (size_t)c * HIDP;
#pragma unroll
    for (int j = 0; j < 5; ++j) {
        int col = lane + 64 * j;
        if (col < HIDP) {
            float h = v[j] + sn * sp[col] + ((col < HID) ? bias[col] : 0.0f);
            out[(size_t)c * HIDP + col] = fmaxf(h, 0.0f);
        }
    }
}

__global__ void k_colsumA(const float* __restrict__ h, float* __restrict__ g_sum) {
    int r0 = blockIdx.x * 64;
    int t = threadIdx.x;
    float s0 = 0.0f, s1 = 0.0f;
    for (int r = 0; r < 64; ++r) {
        int gr = r0 + r;
        if (gr < N_NODES) {
            s0 += h[gr * HIDP + t];
            if (t < HIDP - 256) s1 += h[gr * HIDP + 256 + t];
        }
    }
    if (t < HID) atomicAdd(&g_sum[t], s0);
    if (t < HIDP - 256 && 256 + t < HID) atomicAdd(&g_sum[256 + t], s1);
}

__global__ void k_head(const float* __restrict__ g_sum,
                       const float* __restrict__ lin1_w, const float* __restrict__ lin1_b,
                       const float* __restrict__ lin2_w, const float* __restrict__ lin2_b,
                       float* __restrict__ out) {
    __shared__ float g2[32];
    int t = threadIdx.x;
    const float inv = 1.0f / (float)N_EDGES;
    if (t < 32) {
        float a = lin1_b[t];
        for (int d = 0; d < HID; ++d) a = fmaf(g_sum[d] * inv, lin1_w[d * 32 + t], a);
        g2[t] = fmaxf(a, 0.0f);
    }
    __syncthreads();
    if (t < 2) {
        float p = lin2_b[t];
        for (int j = 0; j < 32; ++j) p = fmaf(g2[j], lin2_w[j * 2 + t], p);
        out[t] = p;
    }
}

// ---------------------------------------------------------------------------

extern "C" void kernel_launch(void* const* d_in, const int* in_sizes, int n_in,
                              void* d_out, int out_size, void* d_ws, size_t ws_size,
                              hipStream_t stream) {
    (void)in_sizes; (void)n_in; (void)out_size; (void)ws_size;
    const int* edge_index = (const int*)d_in[1];
    const float* edge_attr = (const float*)d_in[2];
    const float* edge_w = (const float*)d_in[6];
    const float* edge_b = (const float*)d_in[7];
    const float* gcn0_w = (const float*)d_in[8];
    const float* gcn0_b = (const float*)d_in[9];
    const float* gcn_w = (const float*)d_in[10];
    const float* gcn_b = (const float*)d_in[11];
    const float* lin1_w = (const float*)d_in[12];
    const float* lin1_b = (const float*)d_in[13];
    const float* lin2_w = (const float*)d_in[14];
    const float* lin2_b = (const float*)d_in[15];

    char* ws = (char*)d_ws;
    size_t off = 0;
    auto alloc = [&](size_t bytes) {
        void* p = ws + off;
        off = (off + bytes + 255) & ~(size_t)255;
        return p;
    };
    float* e_buf = (float*)alloc((size_t)N_EDGES * 32 * 4);
    float* hA = (float*)alloc((size_t)N_NODES * HIDP * 4);
    float* hB = (float*)alloc((size_t)N_NODES * HIDP * 4);
    float* hw = (float*)alloc((size_t)N_NODES * HIDP * 4);
    int* row_sorted = (int*)alloc((size_t)N_EDGES * 4);
    float* norm_sorted = (float*)alloc((size_t)N_EDGES * 4);
    int* cnt = (int*)alloc((size_t)N_NODES * 4);
    int* col_start = (int*)alloc((size_t)(N_NODES + 1) * 4);
    int* cursor = (int*)alloc((size_t)N_NODES * 4);
    float* dinv = (float*)alloc((size_t)N_NODES * 4);
    float* selfnorm = (float*)alloc((size_t)N_NODES * 4);
    float* g_sum = (float*)alloc((size_t)HIDP * 4);
    short* wt0 = (short*)alloc((size_t)38912);
    short* wtl = (short*)alloc((size_t)4 * 389120);
    float* g_part = (float*)alloc((size_t)64 * HIDP * 4);

    const int* row = edge_index;
    const int* col = edge_index + N_EDGES;

    hipMemsetAsync(cnt, 0, N_NODES * 4, stream);
    hipMemsetAsync(g_sum, 0, HIDP * 4, stream);
    hipMemsetAsync(g_part, 0, 64 * HIDP * 4, stream);

    k_edge_embed<<<(N_EDGES * 32 + 255) / 256, 256, 0, stream>>>(edge_attr, edge_w, edge_b, e_buf);
    k_wt<<<(1216 + 48640 + 255) / 256, 256, 0, stream>>>(gcn0_w, gcn_w, wt0, wtl);
    k_count<<<(N_EDGES + 255) / 256, 256, 0, stream>>>(col, cnt);
    k_scan<<<1, 256, 0, stream>>>(cnt, col_start, cursor, dinv, selfnorm);
    k_fill<<<(N_EDGES + 255) / 256, 256, 0, stream>>>(row, col, cursor, dinv, row_sorted, norm_sorted);

    // Part B: 3125 blocks x 8 waves, pre-split H planes, MFMA-bound
    k_partB_mfma<<<NPARTB / RB, 512, 0, stream>>>(e_buf, wt0, wtl, gcn0_b, gcn_b, g_part);
    k_gsum<<<2, 256, 0, stream>>>(g_part, g_sum);

    // Part A: coupled top-10000 rows, layer by layer
    const int gA_blocks = (N_NODES + RB - 1) / RB;
    const int aggA_blocks = (N_NODES + 3) / 4;
    k_gemmA<<<gA_blocks, 512, 0, stream>>>(e_buf, 32, 32, 1, wt0, hw);
    k_aggA<<<aggA_blocks, 256, 0, stream>>>(hw, col_start, row_sorted, norm_sorted, selfnorm, gcn0_b, hA);
    float* curr = hA;
    float* next = hB;
    for (int l = 1; l < 5; ++l) {
        k_gemmA<<<gA_blocks, 512, 0, stream>>>(curr, HIDP, HIDP, 10, wtl + (size_t)(l - 1) * 194560, hw);
        k_aggA<<<aggA_blocks, 256, 0, stream>>>(hw, col_start, row_sorted, norm_sorted, selfnorm,
                                                gcn_b + (l - 1) * HID, next);
        float* tmp = curr; curr = next; next = tmp;
    }
    k_colsumA<<<(N_NODES + 63) / 64, 256, 0, stream>>>(curr, g_sum);
    k_head<<<1, 64, 0, stream>>>(g_sum, lin1_w, lin1_b, lin2_w, lin2_b, (float*)d_out);
}